// Round 3
// baseline (1152.000 us; speedup 1.0000x reference)
//
#include <hip/hip_runtime.h>
#include <math.h>

#define NN 50000
#define NE 800000
// DN=64, DE=32, H=4

// ---------------- transpose: dst[j*R+i] = src[i*C+j], src is R x C ----------
__global__ void k_transpose(const float* __restrict__ s, float* __restrict__ d, int R, int C){
  int idx = blockIdx.x * 256 + threadIdx.x;
  if (idx < R * C){
    int i = idx / C;
    int j = idx - i * C;
    d[j * R + i] = s[idx];
  }
}

// ---------------- node projections: p = relu(x @ W + b) ---------------------
__global__ __launch_bounds__(256) void k_node_proj(
    const float* __restrict__ x,
    const float* __restrict__ wtq, const float* __restrict__ bq,
    const float* __restrict__ wtk, const float* __restrict__ bk,
    const float* __restrict__ wtv, const float* __restrict__ bv,
    float* __restrict__ pqk, float* __restrict__ pv){
  int n = blockIdx.x * 256 + threadIdx.x;
  if (n >= NN) return;
  int p = blockIdx.y;
  const float* wt = (p == 0) ? wtq : (p == 1) ? wtk : wtv;
  const float* bb = (p == 0) ? bq  : (p == 1) ? bk  : bv;
  float* out = (p == 0) ? pqk + (size_t)n * 512
             : (p == 1) ? pqk + (size_t)n * 512 + 256
                        : pv  + (size_t)n * 256;
  float xs[64];
  const float4* xv = (const float4*)(x + (size_t)n * 64);
  #pragma unroll
  for (int i = 0; i < 16; i++){
    float4 t = xv[i];
    xs[4*i+0] = t.x; xs[4*i+1] = t.y; xs[4*i+2] = t.z; xs[4*i+3] = t.w;
  }
  for (int j4 = 0; j4 < 64; j4++){
    const float* w0 = wt + (size_t)j4 * 256;  // 4 transposed rows of 64
    float a0 = bb[4*j4+0], a1 = bb[4*j4+1], a2 = bb[4*j4+2], a3 = bb[4*j4+3];
    #pragma unroll
    for (int c = 0; c < 64; c++){
      float xc = xs[c];
      a0 = fmaf(xc, w0[c],       a0);
      a1 = fmaf(xc, w0[64 + c],  a1);
      a2 = fmaf(xc, w0[128 + c], a2);
      a3 = fmaf(xc, w0[192 + c], a3);
    }
    float4 o = { fmaxf(a0, 0.f), fmaxf(a1, 0.f), fmaxf(a2, 0.f), fmaxf(a3, 0.f) };
    *(float4*)(out + 4 * j4) = o;
  }
}

// softmax over s where s = min(exp(dot*inv_scale), 5)
// (reference: s = clip(exp(.), -5, 5); softmax(s) = exp(s-max)/sum)
__device__ __forceinline__ void attn_mix(const float* dots, float inv_scale, float* cg){
  cg[0] = cg[1] = cg[2] = cg[3] = 0.f;
  #pragma unroll
  for (int h = 0; h < 4; h++){
    float sv[4], mx = -1e30f;
    #pragma unroll
    for (int g = 0; g < 4; g++){
      sv[g] = fminf(expf(dots[h*4 + g] * inv_scale), 5.f);
      mx = fmaxf(mx, sv[g]);
    }
    float rs = 0.f;
    #pragma unroll
    for (int g = 0; g < 4; g++){ sv[g] = expf(sv[g] - mx); rs += sv[g]; }
    float ir = 1.f / rs;
    #pragma unroll
    for (int g = 0; g < 4; g++) cg[g] += sv[g] * ir;
  }
  #pragma unroll
  for (int g = 0; g < 4; g++) cg[g] *= 0.25f;
}

// ---------------- per-edge gates + attention coefficients -------------------
// 1 thread/edge: sigmoid gates, atomics into per-node sums, cg[4] -> cg_out.
__global__ __launch_bounds__(256) void k_edge_gate(
    const float* __restrict__ einp, const int* __restrict__ dstv,
    const float* __restrict__ qet, const float* __restrict__ qeb,
    const float* __restrict__ ket, const float* __restrict__ keb,
    float* __restrict__ wsum_q, float* __restrict__ wsum_k,
    int* __restrict__ counts, float* __restrict__ cg_out){
  int e = blockIdx.x * 256 + threadIdx.x;   // NE % 256 == 0
  float es[32];
  const float4* ev4 = (const float4*)(einp + (size_t)e * 32);
  #pragma unroll
  for (int i = 0; i < 8; i++){
    float4 t = ev4[i];
    es[4*i+0] = t.x; es[4*i+1] = t.y; es[4*i+2] = t.z; es[4*i+3] = t.w;
  }
  float qw[4], kw[4];
  #pragma unroll
  for (int h = 0; h < 4; h++){
    float aq = qeb[h], ak = keb[h];
    #pragma unroll
    for (int c = 0; c < 32; c++){
      aq = fmaf(es[c], qet[h*32 + c], aq);
      ak = fmaf(es[c], ket[h*32 + c], ak);
    }
    qw[h] = 1.f / (1.f + expf(-aq));
    kw[h] = 1.f / (1.f + expf(-ak));
  }
  int d = dstv[e];
  #pragma unroll
  for (int h = 0; h < 4; h++){
    atomicAdd(&wsum_q[d*4 + h], qw[h]);
    atomicAdd(&wsum_k[d*4 + h], kw[h]);
  }
  atomicAdd(&counts[d], 1);
  const float inv_scale = 0.17677669529663687f;  // 1/sqrt(32)
  float dots[16];
  #pragma unroll
  for (int h = 0; h < 4; h++)
    #pragma unroll
    for (int g = 0; g < 4; g++) dots[h*4 + g] = qw[h] * kw[g];
  float cg[4];
  attn_mix(dots, inv_scale, cg);
  float4 o = { cg[0], cg[1], cg[2], cg[3] };
  *(float4*)(cg_out + (size_t)e * 4) = o;
}

// ---------------- edge value GEMM + relu + attention mix --------------------
// 256 edges/block. Lane L holds vet rows L and L+64 in registers (64 VGPRs).
// Edge inputs staged in LDS, read wave-uniform (broadcast, conflict-free).
// out[e,d] = sum_g cg[e,g]*relu(v[e,g*32+d]); lanes<32: g={0,2}, >=32: g={1,3};
// cross-half combine via shfl_xor(32); paired edges -> full 256B stores.
__global__ __launch_bounds__(256) void k_edge_gemm(
    const float* __restrict__ einp, const float* __restrict__ cg_in,
    const float* __restrict__ vet, const float* __restrict__ veb,
    float* __restrict__ edge_out){
  __shared__ float es_t[256 * 32];   // 32 KB
  __shared__ float cg_t[256 * 4];    // 4 KB
  int tid  = threadIdx.x;
  int wid  = tid >> 6;
  int lane = tid & 63;
  size_t blk_e = (size_t)blockIdx.x * 256;

  // per-lane weights: rows lane, lane+64 of vet [128][32]
  float w0[32], w1[32];
  {
    const float4* r0 = (const float4*)(vet + lane * 32);
    const float4* r1 = (const float4*)(vet + (lane + 64) * 32);
    #pragma unroll
    for (int i = 0; i < 8; i++){
      float4 a = r0[i], b = r1[i];
      w0[4*i+0]=a.x; w0[4*i+1]=a.y; w0[4*i+2]=a.z; w0[4*i+3]=a.w;
      w1[4*i+0]=b.x; w1[4*i+1]=b.y; w1[4*i+2]=b.z; w1[4*i+3]=b.w;
    }
  }
  float bias0 = veb[lane], bias1 = veb[lane + 64];

  // stage 256 edges of inputs + their cg
  const float4* src4 = (const float4*)(einp + blk_e * 32);
  float4* st4 = (float4*)es_t;
  #pragma unroll
  for (int r = 0; r < 8; r++) st4[r * 256 + tid] = src4[r * 256 + tid];
  ((float4*)cg_t)[tid] = ((const float4*)cg_in)[blk_e + tid];
  __syncthreads();

  int g0 = lane >> 5;  // 0 for lanes<32, 1 for lanes>=32
  for (int i0 = 0; i0 < 64; i0 += 2){
    int ea = wid * 64 + i0;
    const float4* xa4 = (const float4*)(es_t + ea * 32);
    const float4* xb4 = xa4 + 8;
    float a0 = bias0, a1 = bias1, c0 = bias0, c1 = bias1;
    #pragma unroll
    for (int c4 = 0; c4 < 8; c4++){
      float4 xa = xa4[c4], xb = xb4[c4];
      a0 = fmaf(xa.x, w0[4*c4+0], a0);
      a0 = fmaf(xa.y, w0[4*c4+1], a0);
      a0 = fmaf(xa.z, w0[4*c4+2], a0);
      a0 = fmaf(xa.w, w0[4*c4+3], a0);
      a1 = fmaf(xa.x, w1[4*c4+0], a1);
      a1 = fmaf(xa.y, w1[4*c4+1], a1);
      a1 = fmaf(xa.z, w1[4*c4+2], a1);
      a1 = fmaf(xa.w, w1[4*c4+3], a1);
      c0 = fmaf(xb.x, w0[4*c4+0], c0);
      c0 = fmaf(xb.y, w0[4*c4+1], c0);
      c0 = fmaf(xb.z, w0[4*c4+2], c0);
      c0 = fmaf(xb.w, w0[4*c4+3], c0);
      c1 = fmaf(xb.x, w1[4*c4+0], c1);
      c1 = fmaf(xb.y, w1[4*c4+1], c1);
      c1 = fmaf(xb.z, w1[4*c4+2], c1);
      c1 = fmaf(xb.w, w1[4*c4+3], c1);
    }
    float cga0 = cg_t[ea*4 + g0],       cga2 = cg_t[ea*4 + g0 + 2];
    float cgb0 = cg_t[(ea+1)*4 + g0],   cgb2 = cg_t[(ea+1)*4 + g0 + 2];
    float oa = cga0 * fmaxf(a0, 0.f) + cga2 * fmaxf(a1, 0.f);
    float ob = cgb0 * fmaxf(c0, 0.f) + cgb2 * fmaxf(c1, 0.f);
    oa += __shfl_xor(oa, 32, 64);
    ob += __shfl_xor(ob, 32, 64);
    float val = (lane < 32) ? oa : ob;
    edge_out[(blk_e + (size_t)ea) * 32 + lane] = val;
  }
}

// ---------------- CSR build: scan of per-dst counts -------------------------
__global__ __launch_bounds__(1024) void k_scan1(const int* __restrict__ counts,
                                                int* __restrict__ offsets,
                                                int* __restrict__ bsums){
  __shared__ int sd[1024];
  int tid = threadIdx.x;
  int gid = blockIdx.x * 1024 + tid;
  int v = (gid < NN) ? counts[gid] : 0;
  sd[tid] = v;
  __syncthreads();
  for (int off = 1; off < 1024; off <<= 1){
    int t = (tid >= off) ? sd[tid - off] : 0;
    __syncthreads();
    sd[tid] += t;
    __syncthreads();
  }
  int incl = sd[tid];
  if (gid < NN) offsets[gid] = incl - v;
  if (tid == 1023) bsums[blockIdx.x] = incl;
}

__global__ void k_scan2(int* __restrict__ bsums, int nb){
  int run = 0;
  for (int i = 0; i < nb; i++){ int t = bsums[i]; bsums[i] = run; run += t; }
}

__global__ __launch_bounds__(1024) void k_scan3(int* __restrict__ offsets,
                                                const int* __restrict__ bsums){
  int gid = blockIdx.x * 1024 + threadIdx.x;
  if (gid < NN) offsets[gid] += bsums[blockIdx.x];
  if (gid == 0) offsets[NN] = NE;
}

__global__ __launch_bounds__(256) void k_fill(const int* __restrict__ dstv,
                                              const int* __restrict__ offsets,
                                              int* __restrict__ cursor,
                                              int* __restrict__ csr){
  int e = blockIdx.x * 256 + threadIdx.x;
  if (e >= NE) return;
  int d = dstv[e];
  int pos = offsets[d] + atomicAdd(&cursor[d], 1);
  csr[pos] = e;
}

// ---------------- node aggregation + attention + output ---------------------
__global__ __launch_bounds__(256) void k_node_agg(
    const int* __restrict__ srcv, const int* __restrict__ offsets,
    const int* __restrict__ csr,
    const float* __restrict__ pqk, const float* __restrict__ pv,
    const float* __restrict__ wsum_q, const float* __restrict__ wsum_k,
    float* __restrict__ node_out){
  __shared__ float tile[4][512];
  int wid  = threadIdx.x >> 6;
  int lane = threadIdx.x & 63;
  int n = blockIdx.x * 4 + wid;           // NN divisible by 4
  int off0 = offsets[n], off1 = offsets[n + 1];
  float4 qa = {0.f,0.f,0.f,0.f}, ka = {0.f,0.f,0.f,0.f};
  int i = off0;
  int s_cur = 0;
  if (i < off1) s_cur = srcv[csr[i]];
  while (i < off1){
    int s_nxt = (i + 1 < off1) ? srcv[csr[i + 1]] : 0;
    const float4* pr = (const float4*)(pqk + (size_t)s_cur * 512);
    float4 a = pr[lane];
    float4 b = pr[64 + lane];
    qa.x += a.x; qa.y += a.y; qa.z += a.z; qa.w += a.w;
    ka.x += b.x; ka.y += b.y; ka.z += b.z; ka.w += b.w;
    s_cur = s_nxt;
    i++;
  }
  float* tl = tile[wid];
  ((float4*)tl)[lane]      = qa;
  ((float4*)tl)[64 + lane] = ka;
  __syncthreads();
  float qh[4], kh[4];
  int deg = off1 - off0;
  if (deg > 0){
    float inv = 1.f / (float)deg;
    #pragma unroll
    for (int h = 0; h < 4; h++){
      qh[h] = (tl[h*64 + lane]       + wsum_q[n*4 + h]) * inv;
      kh[h] = (tl[256 + h*64 + lane] + wsum_k[n*4 + h]) * inv;
    }
  } else {
    #pragma unroll
    for (int h = 0; h < 4; h++){ qh[h] = 0.f; kh[h] = 0.f; }
  }
  float dots[16];
  #pragma unroll
  for (int h = 0; h < 4; h++)
    #pragma unroll
    for (int g = 0; g < 4; g++) dots[h*4 + g] = qh[h] * kh[g];
  #pragma unroll
  for (int m = 1; m < 64; m <<= 1){
    #pragma unroll
    for (int t = 0; t < 16; t++) dots[t] += __shfl_xor(dots[t], m, 64);
  }
  const float inv_ns = 0.125f;  // 1/sqrt(64)
  float cg[4];
  attn_mix(dots, inv_ns, cg);
  const float* vb = pv + (size_t)n * 256;
  float o = 0.f;
  #pragma unroll
  for (int g = 0; g < 4; g++) o = fmaf(cg[g], vb[g*64 + lane], o);
  node_out[(size_t)n * 64 + lane] = o;
}

// ---------------------------------------------------------------------------
extern "C" void kernel_launch(void* const* d_in, const int* in_sizes, int n_in,
                              void* d_out, int out_size, void* d_ws, size_t ws_size,
                              hipStream_t stream) {
  const float* node_inputs = (const float*)d_in[0];
  const float* edge_inputs = (const float*)d_in[1];
  const int*   srcv        = (const int*)d_in[2];
  const int*   dstv        = (const int*)d_in[3];
  const float* qn_w = (const float*)d_in[4];
  const float* qn_b = (const float*)d_in[5];
  const float* qe_w = (const float*)d_in[6];
  const float* qe_b = (const float*)d_in[7];
  const float* kn_w = (const float*)d_in[8];
  const float* kn_b = (const float*)d_in[9];
  const float* ke_w = (const float*)d_in[10];
  const float* ke_b = (const float*)d_in[11];
  const float* vn_w = (const float*)d_in[12];
  const float* vn_b = (const float*)d_in[13];
  const float* ve_w = (const float*)d_in[14];
  const float* ve_b = (const float*)d_in[15];

  float* out      = (float*)d_out;
  float* node_out = out;                          // [NN,64]
  float* edge_out = out + (size_t)NN * 64;        // [NE,32]

  float* ws = (float*)d_ws;
  float* pqk    = ws;                              // 25,600,000 floats
  float* pv     = pqk + (size_t)NN * 512;          // 12,800,000
  float* wt_qn  = pv + (size_t)NN * 256;           // 16384
  float* wt_kn  = wt_qn + 16384;
  float* wt_vn  = wt_kn + 16384;
  float* wt_ve  = wt_vn + 16384;                   // 4096
  float* wt_qe  = wt_ve + 4096;                    // 128
  float* wt_ke  = wt_qe + 128;                     // 128
  float* wsum_q = wt_ke + 128;                     // 4*NN
  float* wsum_k = wsum_q + (size_t)4 * NN;         // 4*NN
  int* counts   = (int*)(wsum_k + (size_t)4 * NN); // NN
  int* cursor   = counts + NN;                     // NN
  int* offsets  = cursor + NN;                     // NN+1
  int* csr      = offsets + NN + 1;                // NE
  int* bsums    = csr + NE;                        // 64

  // cg scratch [NE,4] aliases the pv region: consumed by k_edge_gemm BEFORE
  // k_node_proj overwrites pv (stream-ordered).
  float* cg_ws = pv;

  // zero wsum_q, wsum_k, counts, cursor (contiguous): 10*NN words
  hipMemsetAsync(wsum_q, 0, (size_t)10 * NN * sizeof(float), stream);

  // weight transposes
  k_transpose<<<(16384 + 255) / 256, 256, 0, stream>>>(qn_w, wt_qn, 64, 256);
  k_transpose<<<(16384 + 255) / 256, 256, 0, stream>>>(kn_w, wt_kn, 64, 256);
  k_transpose<<<(16384 + 255) / 256, 256, 0, stream>>>(vn_w, wt_vn, 64, 256);
  k_transpose<<<(4096  + 255) / 256, 256, 0, stream>>>(ve_w, wt_ve, 32, 128);
  k_transpose<<<1, 256, 0, stream>>>(qe_w, wt_qe, 32, 4);
  k_transpose<<<1, 256, 0, stream>>>(ke_w, wt_ke, 32, 4);

  // edge: gates/atomics/cg, then register-blocked value GEMM
  k_edge_gate<<<NE / 256, 256, 0, stream>>>(
      edge_inputs, dstv, wt_qe, qe_b, wt_ke, ke_b,
      wsum_q, wsum_k, counts, cg_ws);
  k_edge_gemm<<<NE / 256, 256, 0, stream>>>(
      edge_inputs, cg_ws, wt_ve, ve_b, edge_out);

  // node projections (q,k,v) — overwrites pv (cg no longer needed)
  k_node_proj<<<dim3((NN + 255) / 256, 3), 256, 0, stream>>>(
      node_inputs, wt_qn, qn_b, wt_kn, kn_b, wt_vn, vn_b, pqk, pv);

  // CSR build
  const int SB = (NN + 1023) / 1024;  // 49
  k_scan1<<<SB, 1024, 0, stream>>>(counts, offsets, bsums);
  k_scan2<<<1, 1, 0, stream>>>(bsums, SB);
  k_scan3<<<SB, 1024, 0, stream>>>(offsets, bsums);
  k_fill<<<NE / 256, 256, 0, stream>>>(dstv, offsets, cursor, csr);

  // node aggregation + attention + output
  k_node_agg<<<NN / 4, 256, 0, stream>>>(
      srcv, offsets, csr, pqk, pv, wsum_q, wsum_k, node_out);
}

// Round 6
// 871.778 us; speedup vs baseline: 1.3214x; 1.3214x over previous
//
#include <hip/hip_runtime.h>
#include <math.h>

#define NN 50000
#define NE 800000
// DN=64, DE=32, H=4

// bf16 pack/unpack helpers (RNE rounding)
__device__ __forceinline__ unsigned bf16_2(float lo, float hi){
  unsigned a = __float_as_uint(lo), b = __float_as_uint(hi);
  unsigned ra = (a + 0x7fffu + ((a >> 16) & 1u)) >> 16;
  unsigned rb = (b + 0x7fffu + ((b >> 16) & 1u)) >> 16;
  return ra | (rb << 16);
}
__device__ __forceinline__ float bflo(unsigned u){ return __uint_as_float(u << 16); }
__device__ __forceinline__ float bfhi(unsigned u){ return __uint_as_float(u & 0xffff0000u); }

// ---------------- transpose: dst[j*R+i] = src[i*C+j], src is R x C ----------
__global__ void k_transpose(const float* __restrict__ s, float* __restrict__ d, int R, int C){
  int idx = blockIdx.x * 256 + threadIdx.x;
  if (idx < R * C){
    int i = idx / C;
    int j = idx - i * C;
    d[j * R + i] = s[idx];
  }
}

// ---------------- node projections: p = relu(x @ W + b) ---------------------
__global__ __launch_bounds__(256) void k_node_proj(
    const float* __restrict__ x,
    const float* __restrict__ wtq, const float* __restrict__ bq,
    const float* __restrict__ wtk, const float* __restrict__ bk,
    const float* __restrict__ wtv, const float* __restrict__ bv,
    float* __restrict__ pqk, float* __restrict__ pv){
  int n = blockIdx.x * 256 + threadIdx.x;
  if (n >= NN) return;
  int p = blockIdx.y;
  const float* wt = (p == 0) ? wtq : (p == 1) ? wtk : wtv;
  const float* bb = (p == 0) ? bq  : (p == 1) ? bk  : bv;
  float* out = (p == 0) ? pqk + (size_t)n * 512
             : (p == 1) ? pqk + (size_t)n * 512 + 256
                        : pv  + (size_t)n * 256;
  float xs[64];
  const float4* xv = (const float4*)(x + (size_t)n * 64);
  #pragma unroll
  for (int i = 0; i < 16; i++){
    float4 t = xv[i];
    xs[4*i+0] = t.x; xs[4*i+1] = t.y; xs[4*i+2] = t.z; xs[4*i+3] = t.w;
  }
  for (int j4 = 0; j4 < 64; j4++){
    const float* w0 = wt + (size_t)j4 * 256;  // 4 transposed rows of 64
    float a0 = bb[4*j4+0], a1 = bb[4*j4+1], a2 = bb[4*j4+2], a3 = bb[4*j4+3];
    #pragma unroll
    for (int c = 0; c < 64; c++){
      float xc = xs[c];
      a0 = fmaf(xc, w0[c],       a0);
      a1 = fmaf(xc, w0[64 + c],  a1);
      a2 = fmaf(xc, w0[128 + c], a2);
      a3 = fmaf(xc, w0[192 + c], a3);
    }
    float4 o = { fmaxf(a0, 0.f), fmaxf(a1, 0.f), fmaxf(a2, 0.f), fmaxf(a3, 0.f) };
    *(float4*)(out + 4 * j4) = o;
  }
}

// softmax over s where s = min(exp(dot*inv_scale), 5)
// (reference: s = clip(exp(.), -5, 5); softmax(s) = exp(s-max)/sum)
__device__ __forceinline__ void attn_mix(const float* dots, float inv_scale, float* cg){
  cg[0] = cg[1] = cg[2] = cg[3] = 0.f;
  #pragma unroll
  for (int h = 0; h < 4; h++){
    float sv[4], mx = -1e30f;
    #pragma unroll
    for (int g = 0; g < 4; g++){
      sv[g] = fminf(expf(dots[h*4 + g] * inv_scale), 5.f);
      mx = fmaxf(mx, sv[g]);
    }
    float rs = 0.f;
    #pragma unroll
    for (int g = 0; g < 4; g++){ sv[g] = expf(sv[g] - mx); rs += sv[g]; }
    float ir = 1.f / rs;
    #pragma unroll
    for (int g = 0; g < 4; g++) cg[g] += sv[g] * ir;
  }
  #pragma unroll
  for (int g = 0; g < 4; g++) cg[g] *= 0.25f;
}

// ---------------- per-edge gates: sigmoid -> packed bf16, + histogram -------
// Only ONE atomic per edge (the degree histogram). Gate sums are aggregated
// later in k_node_agg via CSR (no scattered fp atomics).
__global__ __launch_bounds__(256) void k_edge_gate(
    const float* __restrict__ einp, const int* __restrict__ dstv,
    const float* __restrict__ qet, const float* __restrict__ qeb,
    const float* __restrict__ ket, const float* __restrict__ keb,
    int* __restrict__ counts, uint4* __restrict__ qwkw){
  int e = blockIdx.x * 256 + threadIdx.x;   // NE % 256 == 0
  float es[32];
  const float4* ev4 = (const float4*)(einp + (size_t)e * 32);
  #pragma unroll
  for (int i = 0; i < 8; i++){
    float4 t = ev4[i];
    es[4*i+0] = t.x; es[4*i+1] = t.y; es[4*i+2] = t.z; es[4*i+3] = t.w;
  }
  float qw[4], kw[4];
  #pragma unroll
  for (int h = 0; h < 4; h++){
    float aq = qeb[h], ak = keb[h];
    #pragma unroll
    for (int c = 0; c < 32; c++){
      aq = fmaf(es[c], qet[h*32 + c], aq);
      ak = fmaf(es[c], ket[h*32 + c], ak);
    }
    qw[h] = 1.f / (1.f + expf(-aq));
    kw[h] = 1.f / (1.f + expf(-ak));
  }
  atomicAdd(&counts[dstv[e]], 1);
  uint4 o;
  o.x = bf16_2(qw[0], qw[1]);
  o.y = bf16_2(qw[2], qw[3]);
  o.z = bf16_2(kw[0], kw[1]);
  o.w = bf16_2(kw[2], kw[3]);
  qwkw[e] = o;
}

// ---------------- edge value GEMM + relu + attention mix --------------------
// 256 edges/block. Lane L holds vet rows L and L+64 in registers (64 VGPRs).
// Edge inputs staged in LDS, read wave-uniform (broadcast, conflict-free).
// cg computed per-thread from packed gates into LDS.
__global__ __launch_bounds__(256) void k_edge_gemm(
    const float* __restrict__ einp, const uint4* __restrict__ qwkw,
    const float* __restrict__ vet, const float* __restrict__ veb,
    float* __restrict__ edge_out){
  __shared__ float es_t[256 * 32];   // 32 KB
  __shared__ float cg_t[256 * 4];    // 4 KB
  int tid  = threadIdx.x;
  int wid  = tid >> 6;
  int lane = tid & 63;
  size_t blk_e = (size_t)blockIdx.x * 256;

  // per-lane weights: rows lane, lane+64 of vet [128][32]
  float w0[32], w1[32];
  {
    const float4* r0 = (const float4*)(vet + lane * 32);
    const float4* r1 = (const float4*)(vet + (lane + 64) * 32);
    #pragma unroll
    for (int i = 0; i < 8; i++){
      float4 a = r0[i], b = r1[i];
      w0[4*i+0]=a.x; w0[4*i+1]=a.y; w0[4*i+2]=a.z; w0[4*i+3]=a.w;
      w1[4*i+0]=b.x; w1[4*i+1]=b.y; w1[4*i+2]=b.z; w1[4*i+3]=b.w;
    }
  }
  float bias0 = veb[lane], bias1 = veb[lane + 64];

  // stage 256 edges of inputs
  const float4* src4 = (const float4*)(einp + blk_e * 32);
  float4* st4 = (float4*)es_t;
  #pragma unroll
  for (int r = 0; r < 8; r++) st4[r * 256 + tid] = src4[r * 256 + tid];
  // per-thread: compute cg for edge (blk_e + tid) from packed gates
  {
    uint4 qk = qwkw[blk_e + tid];
    float qw[4] = { bflo(qk.x), bfhi(qk.x), bflo(qk.y), bfhi(qk.y) };
    float kw[4] = { bflo(qk.z), bfhi(qk.z), bflo(qk.w), bfhi(qk.w) };
    const float inv_scale = 0.17677669529663687f;  // 1/sqrt(32)
    float dots[16];
    #pragma unroll
    for (int h = 0; h < 4; h++)
      #pragma unroll
      for (int g = 0; g < 4; g++) dots[h*4 + g] = qw[h] * kw[g];
    float cg[4];
    attn_mix(dots, inv_scale, cg);
    float4 o = { cg[0], cg[1], cg[2], cg[3] };
    *(float4*)(cg_t + tid * 4) = o;
  }
  __syncthreads();

  int g0 = lane >> 5;  // 0 for lanes<32, 1 for lanes>=32
  for (int i0 = 0; i0 < 64; i0 += 2){
    int ea = wid * 64 + i0;
    const float4* xa4 = (const float4*)(es_t + ea * 32);
    const float4* xb4 = xa4 + 8;
    float a0 = bias0, a1 = bias1, c0 = bias0, c1 = bias1;
    #pragma unroll
    for (int c4 = 0; c4 < 8; c4++){
      float4 xa = xa4[c4], xb = xb4[c4];
      a0 = fmaf(xa.x, w0[4*c4+0], a0);
      a0 = fmaf(xa.y, w0[4*c4+1], a0);
      a0 = fmaf(xa.z, w0[4*c4+2], a0);
      a0 = fmaf(xa.w, w0[4*c4+3], a0);
      a1 = fmaf(xa.x, w1[4*c4+0], a1);
      a1 = fmaf(xa.y, w1[4*c4+1], a1);
      a1 = fmaf(xa.z, w1[4*c4+2], a1);
      a1 = fmaf(xa.w, w1[4*c4+3], a1);
      c0 = fmaf(xb.x, w0[4*c4+0], c0);
      c0 = fmaf(xb.y, w0[4*c4+1], c0);
      c0 = fmaf(xb.z, w0[4*c4+2], c0);
      c0 = fmaf(xb.w, w0[4*c4+3], c0);
      c1 = fmaf(xb.x, w1[4*c4+0], c1);
      c1 = fmaf(xb.y, w1[4*c4+1], c1);
      c1 = fmaf(xb.z, w1[4*c4+2], c1);
      c1 = fmaf(xb.w, w1[4*c4+3], c1);
    }
    float cga0 = cg_t[ea*4 + g0],       cga2 = cg_t[ea*4 + g0 + 2];
    float cgb0 = cg_t[(ea+1)*4 + g0],   cgb2 = cg_t[(ea+1)*4 + g0 + 2];
    float oa = cga0 * fmaxf(a0, 0.f) + cga2 * fmaxf(a1, 0.f);
    float ob = cgb0 * fmaxf(c0, 0.f) + cgb2 * fmaxf(c1, 0.f);
    oa += __shfl_xor(oa, 32, 64);
    ob += __shfl_xor(ob, 32, 64);
    float val = (lane < 32) ? oa : ob;
    edge_out[(blk_e + (size_t)ea) * 32 + lane] = val;
  }
}

// ---------------- CSR build: scan of per-dst counts -------------------------
__global__ __launch_bounds__(1024) void k_scan1(const int* __restrict__ counts,
                                                int* __restrict__ offsets,
                                                int* __restrict__ bsums){
  __shared__ int sd[1024];
  int tid = threadIdx.x;
  int gid = blockIdx.x * 1024 + tid;
  int v = (gid < NN) ? counts[gid] : 0;
  sd[tid] = v;
  __syncthreads();
  for (int off = 1; off < 1024; off <<= 1){
    int t = (tid >= off) ? sd[tid - off] : 0;
    __syncthreads();
    sd[tid] += t;
    __syncthreads();
  }
  int incl = sd[tid];
  if (gid < NN) offsets[gid] = incl - v;
  if (tid == 1023) bsums[blockIdx.x] = incl;
}

__global__ void k_scan2(int* __restrict__ bsums, int nb){
  int run = 0;
  for (int i = 0; i < nb; i++){ int t = bsums[i]; bsums[i] = run; run += t; }
}

__global__ __launch_bounds__(1024) void k_scan3(int* __restrict__ offsets,
                                                const int* __restrict__ bsums){
  int gid = blockIdx.x * 1024 + threadIdx.x;
  if (gid < NN) offsets[gid] += bsums[blockIdx.x];
  if (gid == 0) offsets[NN] = NE;
}

__global__ __launch_bounds__(256) void k_fill(const int* __restrict__ dstv,
                                              const int* __restrict__ offsets,
                                              int* __restrict__ cursor,
                                              int* __restrict__ csr){
  int e = blockIdx.x * 256 + threadIdx.x;
  if (e >= NE) return;
  int d = dstv[e];
  int pos = offsets[d] + atomicAdd(&cursor[d], 1);
  csr[pos] = e;
}

// ---------------- node aggregation + attention + output ---------------------
// one wave per node; gate sums accumulated in registers from packed qwkw.
__global__ __launch_bounds__(256) void k_node_agg(
    const int* __restrict__ srcv, const int* __restrict__ offsets,
    const int* __restrict__ csr, const uint4* __restrict__ qwkw,
    const float* __restrict__ pqk, const float* __restrict__ pv,
    float* __restrict__ node_out){
  __shared__ float tile[4][512];
  int wid  = threadIdx.x >> 6;
  int lane = threadIdx.x & 63;
  int n = blockIdx.x * 4 + wid;           // NN divisible by 4
  int off0 = offsets[n], off1 = offsets[n + 1];
  float4 qa = {0.f,0.f,0.f,0.f}, ka = {0.f,0.f,0.f,0.f};
  float qs0=0.f,qs1=0.f,qs2=0.f,qs3=0.f, ks0=0.f,ks1=0.f,ks2=0.f,ks3=0.f;
  int i = off0;
  int e_cur = 0, s_cur = 0;
  if (i < off1){ e_cur = csr[i]; s_cur = srcv[e_cur]; }
  while (i < off1){
    int e_nxt = 0, s_nxt = 0;
    if (i + 1 < off1){ e_nxt = csr[i + 1]; s_nxt = srcv[e_nxt]; }
    const float4* pr = (const float4*)(pqk + (size_t)s_cur * 512);
    float4 a = pr[lane];
    float4 b = pr[64 + lane];
    uint4 qk = qwkw[e_cur];       // wave-uniform address -> broadcast
    qa.x += a.x; qa.y += a.y; qa.z += a.z; qa.w += a.w;
    ka.x += b.x; ka.y += b.y; ka.z += b.z; ka.w += b.w;
    qs0 += bflo(qk.x); qs1 += bfhi(qk.x); qs2 += bflo(qk.y); qs3 += bfhi(qk.y);
    ks0 += bflo(qk.z); ks1 += bfhi(qk.z); ks2 += bflo(qk.w); ks3 += bfhi(qk.w);
    e_cur = e_nxt; s_cur = s_nxt;
    i++;
  }
  float* tl = tile[wid];
  ((float4*)tl)[lane]      = qa;
  ((float4*)tl)[64 + lane] = ka;
  __syncthreads();
  float qh[4], kh[4];
  int deg = off1 - off0;
  float qsv[4] = { qs0, qs1, qs2, qs3 };
  float ksv[4] = { ks0, ks1, ks2, ks3 };
  if (deg > 0){
    float inv = 1.f / (float)deg;
    #pragma unroll
    for (int h = 0; h < 4; h++){
      qh[h] = (tl[h*64 + lane]       + qsv[h]) * inv;
      kh[h] = (tl[256 + h*64 + lane] + ksv[h]) * inv;
    }
  } else {
    #pragma unroll
    for (int h = 0; h < 4; h++){ qh[h] = 0.f; kh[h] = 0.f; }
  }
  float dots[16];
  #pragma unroll
  for (int h = 0; h < 4; h++)
    #pragma unroll
    for (int g = 0; g < 4; g++) dots[h*4 + g] = qh[h] * kh[g];
  #pragma unroll
  for (int m = 1; m < 64; m <<= 1){
    #pragma unroll
    for (int t = 0; t < 16; t++) dots[t] += __shfl_xor(dots[t], m, 64);
  }
  const float inv_ns = 0.125f;  // 1/sqrt(64)
  float cg[4];
  attn_mix(dots, inv_ns, cg);
  const float* vb = pv + (size_t)n * 256;
  float o = 0.f;
  #pragma unroll
  for (int g = 0; g < 4; g++) o = fmaf(cg[g], vb[g*64 + lane], o);
  node_out[(size_t)n * 64 + lane] = o;
}

// ---------------------------------------------------------------------------
extern "C" void kernel_launch(void* const* d_in, const int* in_sizes, int n_in,
                              void* d_out, int out_size, void* d_ws, size_t ws_size,
                              hipStream_t stream) {
  const float* node_inputs = (const float*)d_in[0];
  const float* edge_inputs = (const float*)d_in[1];
  const int*   srcv        = (const int*)d_in[2];
  const int*   dstv        = (const int*)d_in[3];
  const float* qn_w = (const float*)d_in[4];
  const float* qn_b = (const float*)d_in[5];
  const float* qe_w = (const float*)d_in[6];
  const float* qe_b = (const float*)d_in[7];
  const float* kn_w = (const float*)d_in[8];
  const float* kn_b = (const float*)d_in[9];
  const float* ke_w = (const float*)d_in[10];
  const float* ke_b = (const float*)d_in[11];
  const float* vn_w = (const float*)d_in[12];
  const float* vn_b = (const float*)d_in[13];
  const float* ve_w = (const float*)d_in[14];
  const float* ve_b = (const float*)d_in[15];

  float* out      = (float*)d_out;
  float* node_out = out;                          // [NN,64]
  float* edge_out = out + (size_t)NN * 64;        // [NE,32]

  float* ws = (float*)d_ws;
  float* pqk    = ws;                              // NN*512 floats
  float* pv     = pqk + (size_t)NN * 512;          // NN*256
  uint4* qwkw   = (uint4*)(pv + (size_t)NN * 256); // NE uint4 (16B-aligned)
  float* wt_qn  = (float*)(qwkw + NE);             // 16384
  float* wt_kn  = wt_qn + 16384;
  float* wt_vn  = wt_kn + 16384;
  float* wt_ve  = wt_vn + 16384;                   // 4096
  float* wt_qe  = wt_ve + 4096;                    // 128
  float* wt_ke  = wt_qe + 128;                     // 128
  int* counts   = (int*)(wt_ke + 128);             // NN
  int* cursor   = counts + NN;                     // NN
  int* offsets  = cursor + NN;                     // NN+1
  int* csr      = offsets + NN + 1;                // NE
  int* bsums    = csr + NE;                        // 64

  // zero counts + cursor (contiguous)
  hipMemsetAsync(counts, 0, (size_t)2 * NN * sizeof(int), stream);

  // weight transposes
  k_transpose<<<(16384 + 255) / 256, 256, 0, stream>>>(qn_w, wt_qn, 64, 256);
  k_transpose<<<(16384 + 255) / 256, 256, 0, stream>>>(kn_w, wt_kn, 64, 256);
  k_transpose<<<(16384 + 255) / 256, 256, 0, stream>>>(vn_w, wt_vn, 64, 256);
  k_transpose<<<(4096  + 255) / 256, 256, 0, stream>>>(ve_w, wt_ve, 32, 128);
  k_transpose<<<1, 256, 0, stream>>>(qe_w, wt_qe, 32, 4);
  k_transpose<<<1, 256, 0, stream>>>(ke_w, wt_ke, 32, 4);

  // edge gates (1 atomic/edge) then value GEMM (einp stays hot in L3)
  k_edge_gate<<<NE / 256, 256, 0, stream>>>(
      edge_inputs, dstv, wt_qe, qe_b, wt_ke, ke_b, counts, qwkw);
  k_edge_gemm<<<NE / 256, 256, 0, stream>>>(
      edge_inputs, qwkw, wt_ve, ve_b, edge_out);

  // node projections (q,k,v)
  k_node_proj<<<dim3((NN + 255) / 256, 3), 256, 0, stream>>>(
      node_inputs, wt_qn, qn_b, wt_kn, kn_b, wt_vn, vn_b, pqk, pv);

  // CSR build
  const int SB = (NN + 1023) / 1024;  // 49
  k_scan1<<<SB, 1024, 0, stream>>>(counts, offsets, bsums);
  k_scan2<<<1, 1, 0, stream>>>(bsums, SB);
  k_scan3<<<SB, 1024, 0, stream>>>(offsets, bsums);
  k_fill<<<NE / 256, 256, 0, stream>>>(dstv, offsets, cursor, csr);

  // node aggregation + attention + output
  k_node_agg<<<NN / 4, 256, 0, stream>>>(
      srcv, offsets, csr, qwkw, pqk, pv, node_out);
}

// Round 9
// 771.945 us; speedup vs baseline: 1.4923x; 1.1293x over previous
//
#include <hip/hip_runtime.h>
#include <math.h>

#define NN 50000
#define NE 800000
// DN=64, DE=32, H=4

// bf16 pack/unpack helpers (RNE rounding)
__device__ __forceinline__ unsigned bf16_2(float lo, float hi){
  unsigned a = __float_as_uint(lo), b = __float_as_uint(hi);
  unsigned ra = (a + 0x7fffu + ((a >> 16) & 1u)) >> 16;
  unsigned rb = (b + 0x7fffu + ((b >> 16) & 1u)) >> 16;
  return ra | (rb << 16);
}
__device__ __forceinline__ float bflo(unsigned u){ return __uint_as_float(u << 16); }
__device__ __forceinline__ float bfhi(unsigned u){ return __uint_as_float(u & 0xffff0000u); }

// ---------------- all weight transposes in one launch -----------------------
// tasks: 3x (64x256) node weights, 1x (32x128) ve, 2x (32x4) qe/ke
__global__ __launch_bounds__(256) void k_transpose_all(
    const float* __restrict__ qnw, const float* __restrict__ knw,
    const float* __restrict__ vnw, const float* __restrict__ vew,
    const float* __restrict__ qew, const float* __restrict__ kew,
    float* __restrict__ wqn, float* __restrict__ wkn, float* __restrict__ wvn,
    float* __restrict__ wve, float* __restrict__ wqe, float* __restrict__ wke){
  int b = blockIdx.x;
  const float* s; float* d; int R, C, base;
  if (b < 64)       { s = qnw; d = wqn; R = 64; C = 256; base = b; }
  else if (b < 128) { s = knw; d = wkn; R = 64; C = 256; base = b - 64; }
  else if (b < 192) { s = vnw; d = wvn; R = 64; C = 256; base = b - 128; }
  else if (b < 208) { s = vew; d = wve; R = 32; C = 128; base = b - 192; }
  else if (b == 208){ s = qew; d = wqe; R = 32; C = 4;   base = 0; }
  else              { s = kew; d = wke; R = 32; C = 4;   base = 0; }
  int idx = base * 256 + threadIdx.x;
  if (idx < R * C){
    int i = idx / C;
    int j = idx - i * C;
    d[j * R + i] = s[idx];
  }
}

// ---------------- node projections: p = relu(x @ W + b) ---------------------
// p=0 (q) / p=1 (k): packed bf16 into lane-interleaved pqk rows:
//   row n = 64 cells x 16B; cell l = {q[4l..4l+3], k[4l..4l+3]} bf16.
// p=2 (v): fp32 into pv.
__global__ __launch_bounds__(256) void k_node_proj(
    const float* __restrict__ x,
    const float* __restrict__ wtq, const float* __restrict__ bq,
    const float* __restrict__ wtk, const float* __restrict__ bk,
    const float* __restrict__ wtv, const float* __restrict__ bv,
    unsigned* __restrict__ pqk, float* __restrict__ pv){
  int n = blockIdx.x * 256 + threadIdx.x;
  if (n >= NN) return;
  int p = blockIdx.y;
  const float* wt = (p == 0) ? wtq : (p == 1) ? wtk : wtv;
  const float* bb = (p == 0) ? bq  : (p == 1) ? bk  : bv;
  float xs[64];
  const float4* xv = (const float4*)(x + (size_t)n * 64);
  #pragma unroll
  for (int i = 0; i < 16; i++){
    float4 t = xv[i];
    xs[4*i+0] = t.x; xs[4*i+1] = t.y; xs[4*i+2] = t.z; xs[4*i+3] = t.w;
  }
  for (int j4 = 0; j4 < 64; j4++){
    const float* w0 = wt + (size_t)j4 * 256;  // 4 transposed rows of 64
    float a0 = bb[4*j4+0], a1 = bb[4*j4+1], a2 = bb[4*j4+2], a3 = bb[4*j4+3];
    #pragma unroll
    for (int c = 0; c < 64; c++){
      float xc = xs[c];
      a0 = fmaf(xc, w0[c],       a0);
      a1 = fmaf(xc, w0[64 + c],  a1);
      a2 = fmaf(xc, w0[128 + c], a2);
      a3 = fmaf(xc, w0[192 + c], a3);
    }
    a0 = fmaxf(a0, 0.f); a1 = fmaxf(a1, 0.f);
    a2 = fmaxf(a2, 0.f); a3 = fmaxf(a3, 0.f);
    if (p == 2){
      float4 o = { a0, a1, a2, a3 };
      *(float4*)(pv + (size_t)n * 256 + 4 * j4) = o;
    } else {
      uint2 o = { bf16_2(a0, a1), bf16_2(a2, a3) };
      *(uint2*)(pqk + (size_t)n * 256 + j4 * 4 + (p == 1 ? 2 : 0)) = o;
    }
  }
}

// softmax over s where s = min(exp(dot*inv_scale), 5)
// (reference: s = clip(exp(.), -5, 5); softmax(s) = exp(s-max)/sum)
__device__ __forceinline__ void attn_mix(const float* dots, float inv_scale, float* cg){
  cg[0] = cg[1] = cg[2] = cg[3] = 0.f;
  #pragma unroll
  for (int h = 0; h < 4; h++){
    float sv[4], mx = -1e30f;
    #pragma unroll
    for (int g = 0; g < 4; g++){
      sv[g] = fminf(expf(dots[h*4 + g] * inv_scale), 5.f);
      mx = fmaxf(mx, sv[g]);
    }
    float rs = 0.f;
    #pragma unroll
    for (int g = 0; g < 4; g++){ sv[g] = expf(sv[g] - mx); rs += sv[g]; }
    float ir = 1.f / rs;
    #pragma unroll
    for (int g = 0; g < 4; g++) cg[g] += sv[g] * ir;
  }
  #pragma unroll
  for (int g = 0; g < 4; g++) cg[g] *= 0.25f;
}

// ---------------- per-edge gates: sigmoid -> packed bf16, + histogram -------
__global__ __launch_bounds__(256) void k_edge_gate(
    const float* __restrict__ einp, const int* __restrict__ dstv,
    const float* __restrict__ qet, const float* __restrict__ qeb,
    const float* __restrict__ ket, const float* __restrict__ keb,
    int* __restrict__ counts, uint4* __restrict__ qwkw){
  int e = blockIdx.x * 256 + threadIdx.x;   // NE % 256 == 0
  float es[32];
  const float4* ev4 = (const float4*)(einp + (size_t)e * 32);
  #pragma unroll
  for (int i = 0; i < 8; i++){
    float4 t = ev4[i];
    es[4*i+0] = t.x; es[4*i+1] = t.y; es[4*i+2] = t.z; es[4*i+3] = t.w;
  }
  float qw[4], kw[4];
  #pragma unroll
  for (int h = 0; h < 4; h++){
    float aq = qeb[h], ak = keb[h];
    #pragma unroll
    for (int c = 0; c < 32; c++){
      aq = fmaf(es[c], qet[h*32 + c], aq);
      ak = fmaf(es[c], ket[h*32 + c], ak);
    }
    qw[h] = 1.f / (1.f + expf(-aq));
    kw[h] = 1.f / (1.f + expf(-ak));
  }
  atomicAdd(&counts[dstv[e]], 1);
  uint4 o;
  o.x = bf16_2(qw[0], qw[1]);
  o.y = bf16_2(qw[2], qw[3]);
  o.z = bf16_2(kw[0], kw[1]);
  o.w = bf16_2(kw[2], kw[3]);
  qwkw[e] = o;
}

// ---------------- edge value GEMM + relu + attention mix --------------------
__global__ __launch_bounds__(256) void k_edge_gemm(
    const float* __restrict__ einp, const uint4* __restrict__ qwkw,
    const float* __restrict__ vet, const float* __restrict__ veb,
    float* __restrict__ edge_out){
  __shared__ float es_t[256 * 32];   // 32 KB
  __shared__ float cg_t[256 * 4];    // 4 KB
  int tid  = threadIdx.x;
  int wid  = tid >> 6;
  int lane = tid & 63;
  size_t blk_e = (size_t)blockIdx.x * 256;

  // per-lane weights: rows lane, lane+64 of vet [128][32]
  float w0[32], w1[32];
  {
    const float4* r0 = (const float4*)(vet + lane * 32);
    const float4* r1 = (const float4*)(vet + (lane + 64) * 32);
    #pragma unroll
    for (int i = 0; i < 8; i++){
      float4 a = r0[i], b = r1[i];
      w0[4*i+0]=a.x; w0[4*i+1]=a.y; w0[4*i+2]=a.z; w0[4*i+3]=a.w;
      w1[4*i+0]=b.x; w1[4*i+1]=b.y; w1[4*i+2]=b.z; w1[4*i+3]=b.w;
    }
  }
  float bias0 = veb[lane], bias1 = veb[lane + 64];

  // stage 256 edges of inputs
  const float4* src4 = (const float4*)(einp + blk_e * 32);
  float4* st4 = (float4*)es_t;
  #pragma unroll
  for (int r = 0; r < 8; r++) st4[r * 256 + tid] = src4[r * 256 + tid];
  // per-thread: compute cg for edge (blk_e + tid) from packed gates
  {
    uint4 qk = qwkw[blk_e + tid];
    float qw[4] = { bflo(qk.x), bfhi(qk.x), bflo(qk.y), bfhi(qk.y) };
    float kw[4] = { bflo(qk.z), bfhi(qk.z), bflo(qk.w), bfhi(qk.w) };
    const float inv_scale = 0.17677669529663687f;  // 1/sqrt(32)
    float dots[16];
    #pragma unroll
    for (int h = 0; h < 4; h++)
      #pragma unroll
      for (int g = 0; g < 4; g++) dots[h*4 + g] = qw[h] * kw[g];
    float cg[4];
    attn_mix(dots, inv_scale, cg);
    float4 o = { cg[0], cg[1], cg[2], cg[3] };
    *(float4*)(cg_t + tid * 4) = o;
  }
  __syncthreads();

  int g0 = lane >> 5;  // 0 for lanes<32, 1 for lanes>=32
  for (int i0 = 0; i0 < 64; i0 += 2){
    int ea = wid * 64 + i0;
    const float4* xa4 = (const float4*)(es_t + ea * 32);
    const float4* xb4 = xa4 + 8;
    float a0 = bias0, a1 = bias1, c0 = bias0, c1 = bias1;
    #pragma unroll
    for (int c4 = 0; c4 < 8; c4++){
      float4 xa = xa4[c4], xb = xb4[c4];
      a0 = fmaf(xa.x, w0[4*c4+0], a0);
      a0 = fmaf(xa.y, w0[4*c4+1], a0);
      a0 = fmaf(xa.z, w0[4*c4+2], a0);
      a0 = fmaf(xa.w, w0[4*c4+3], a0);
      a1 = fmaf(xa.x, w1[4*c4+0], a1);
      a1 = fmaf(xa.y, w1[4*c4+1], a1);
      a1 = fmaf(xa.z, w1[4*c4+2], a1);
      a1 = fmaf(xa.w, w1[4*c4+3], a1);
      c0 = fmaf(xb.x, w0[4*c4+0], c0);
      c0 = fmaf(xb.y, w0[4*c4+1], c0);
      c0 = fmaf(xb.z, w0[4*c4+2], c0);
      c0 = fmaf(xb.w, w0[4*c4+3], c0);
      c1 = fmaf(xb.x, w1[4*c4+0], c1);
      c1 = fmaf(xb.y, w1[4*c4+1], c1);
      c1 = fmaf(xb.z, w1[4*c4+2], c1);
      c1 = fmaf(xb.w, w1[4*c4+3], c1);
    }
    float cga0 = cg_t[ea*4 + g0],       cga2 = cg_t[ea*4 + g0 + 2];
    float cgb0 = cg_t[(ea+1)*4 + g0],   cgb2 = cg_t[(ea+1)*4 + g0 + 2];
    float oa = cga0 * fmaxf(a0, 0.f) + cga2 * fmaxf(a1, 0.f);
    float ob = cgb0 * fmaxf(c0, 0.f) + cgb2 * fmaxf(c1, 0.f);
    oa += __shfl_xor(oa, 32, 64);
    ob += __shfl_xor(ob, 32, 64);
    float val = (lane < 32) ? oa : ob;
    edge_out[(blk_e + (size_t)ea) * 32 + lane] = val;
  }
}

// ---------------- CSR build: scan of per-dst counts -------------------------
__global__ __launch_bounds__(1024) void k_scan1(const int* __restrict__ counts,
                                                int* __restrict__ offsets,
                                                int* __restrict__ bsums){
  __shared__ int sd[1024];
  int tid = threadIdx.x;
  int gid = blockIdx.x * 1024 + tid;
  int v = (gid < NN) ? counts[gid] : 0;
  sd[tid] = v;
  __syncthreads();
  for (int off = 1; off < 1024; off <<= 1){
    int t = (tid >= off) ? sd[tid - off] : 0;
    __syncthreads();
    sd[tid] += t;
    __syncthreads();
  }
  int incl = sd[tid];
  if (gid < NN) offsets[gid] = incl - v;
  if (tid == 1023) bsums[blockIdx.x] = incl;
}

// one wave: exclusive scan of <=64 block sums
__global__ void k_scan2(int* __restrict__ bsums, int nb){
  int tid = threadIdx.x;
  int v = (tid < nb) ? bsums[tid] : 0;
  for (int off = 1; off < 64; off <<= 1){
    int t = __shfl_up(v, off, 64);
    if (tid >= off) v += t;
  }
  int ex = __shfl_up(v, 1, 64);
  if (tid == 0) ex = 0;
  if (tid < nb) bsums[tid] = ex;
}

__global__ __launch_bounds__(1024) void k_scan3(int* __restrict__ offsets,
                                                const int* __restrict__ bsums){
  int gid = blockIdx.x * 1024 + threadIdx.x;
  if (gid < NN) offsets[gid] += bsums[blockIdx.x];
  if (gid == 0) offsets[NN] = NE;
}

// fill CSR with {edge, src} pairs so agg avoids a dependent srcv load
__global__ __launch_bounds__(256) void k_fill(
    const int* __restrict__ dstv, const int* __restrict__ srcv,
    const int* __restrict__ offsets, int* __restrict__ cursor,
    int2* __restrict__ csr2){
  int e = blockIdx.x * 256 + threadIdx.x;
  if (e >= NE) return;
  int d = dstv[e];
  int s = srcv[e];
  int pos = offsets[d] + atomicAdd(&cursor[d], 1);
  csr2[pos] = make_int2(e, s);
}

// ---------------- node aggregation + attention + output ---------------------
// one wave per node; bf16 pqk gather (1 dwordx4/lane/edge), fp32 accumulate.
__global__ __launch_bounds__(256) void k_node_agg(
    const int* __restrict__ offsets, const int2* __restrict__ csr2,
    const uint4* __restrict__ qwkw, const uint4* __restrict__ pqk,
    const float* __restrict__ pv, float* __restrict__ node_out){
  __shared__ float tile[4][512];
  int wid  = threadIdx.x >> 6;
  int lane = threadIdx.x & 63;
  int n = blockIdx.x * 4 + wid;           // NN divisible by 4
  int off0 = offsets[n], off1 = offsets[n + 1];
  float4 qa = {0.f,0.f,0.f,0.f}, ka = {0.f,0.f,0.f,0.f};
  float qs0=0.f,qs1=0.f,qs2=0.f,qs3=0.f, ks0=0.f,ks1=0.f,ks2=0.f,ks3=0.f;
  int i = off0;
  while (i + 2 <= off1){
    int2 Ea = csr2[i], Eb = csr2[i + 1];
    uint4 ua = pqk[(size_t)Ea.y * 64 + lane];
    uint4 ub = pqk[(size_t)Eb.y * 64 + lane];
    uint4 ga = qwkw[Ea.x];
    uint4 gb = qwkw[Eb.x];
    qa.x += bflo(ua.x); qa.y += bfhi(ua.x); qa.z += bflo(ua.y); qa.w += bfhi(ua.y);
    ka.x += bflo(ua.z); ka.y += bfhi(ua.z); ka.z += bflo(ua.w); ka.w += bfhi(ua.w);
    qa.x += bflo(ub.x); qa.y += bfhi(ub.x); qa.z += bflo(ub.y); qa.w += bfhi(ub.y);
    ka.x += bflo(ub.z); ka.y += bfhi(ub.z); ka.z += bflo(ub.w); ka.w += bfhi(ub.w);
    qs0 += bflo(ga.x) + bflo(gb.x); qs1 += bfhi(ga.x) + bfhi(gb.x);
    qs2 += bflo(ga.y) + bflo(gb.y); qs3 += bfhi(ga.y) + bfhi(gb.y);
    ks0 += bflo(ga.z) + bflo(gb.z); ks1 += bfhi(ga.z) + bfhi(gb.z);
    ks2 += bflo(ga.w) + bflo(gb.w); ks3 += bfhi(ga.w) + bfhi(gb.w);
    i += 2;
  }
  if (i < off1){
    int2 Ea = csr2[i];
    uint4 ua = pqk[(size_t)Ea.y * 64 + lane];
    uint4 ga = qwkw[Ea.x];
    qa.x += bflo(ua.x); qa.y += bfhi(ua.x); qa.z += bflo(ua.y); qa.w += bfhi(ua.y);
    ka.x += bflo(ua.z); ka.y += bfhi(ua.z); ka.z += bflo(ua.w); ka.w += bfhi(ua.w);
    qs0 += bflo(ga.x); qs1 += bfhi(ga.x); qs2 += bflo(ga.y); qs3 += bfhi(ga.y);
    ks0 += bflo(ga.z); ks1 += bfhi(ga.z); ks2 += bflo(ga.w); ks3 += bfhi(ga.w);
  }
  float* tl = tile[wid];
  ((float4*)tl)[lane]      = qa;   // tl[4l+j] = ssum_q[dim 4l+j]
  ((float4*)tl)[64 + lane] = ka;
  __syncthreads();
  float qh[4], kh[4];
  int deg = off1 - off0;
  float qsv[4] = { qs0, qs1, qs2, qs3 };
  float ksv[4] = { ks0, ks1, ks2, ks3 };
  if (deg > 0){
    float inv = 1.f / (float)deg;
    #pragma unroll
    for (int h = 0; h < 4; h++){
      qh[h] = (tl[h*64 + lane]       + qsv[h]) * inv;
      kh[h] = (tl[256 + h*64 + lane] + ksv[h]) * inv;
    }
  } else {
    #pragma unroll
    for (int h = 0; h < 4; h++){ qh[h] = 0.f; kh[h] = 0.f; }
  }
  float dots[16];
  #pragma unroll
  for (int h = 0; h < 4; h++)
    #pragma unroll
    for (int g = 0; g < 4; g++) dots[h*4 + g] = qh[h] * kh[g];
  #pragma unroll
  for (int m = 1; m < 64; m <<= 1){
    #pragma unroll
    for (int t = 0; t < 16; t++) dots[t] += __shfl_xor(dots[t], m, 64);
  }
  const float inv_ns = 0.125f;  // 1/sqrt(64)
  float cg[4];
  attn_mix(dots, inv_ns, cg);
  const float* vb = pv + (size_t)n * 256;
  float o = 0.f;
  #pragma unroll
  for (int g = 0; g < 4; g++) o = fmaf(cg[g], vb[g*64 + lane], o);
  node_out[(size_t)n * 64 + lane] = o;
}

// ---------------------------------------------------------------------------
extern "C" void kernel_launch(void* const* d_in, const int* in_sizes, int n_in,
                              void* d_out, int out_size, void* d_ws, size_t ws_size,
                              hipStream_t stream) {
  const float* node_inputs = (const float*)d_in[0];
  const float* edge_inputs = (const float*)d_in[1];
  const int*   srcv        = (const int*)d_in[2];
  const int*   dstv        = (const int*)d_in[3];
  const float* qn_w = (const float*)d_in[4];
  const float* qn_b = (const float*)d_in[5];
  const float* qe_w = (const float*)d_in[6];
  const float* qe_b = (const float*)d_in[7];
  const float* kn_w = (const float*)d_in[8];
  const float* kn_b = (const float*)d_in[9];
  const float* ke_w = (const float*)d_in[10];
  const float* ke_b = (const float*)d_in[11];
  const float* vn_w = (const float*)d_in[12];
  const float* vn_b = (const float*)d_in[13];
  const float* ve_w = (const float*)d_in[14];
  const float* ve_b = (const float*)d_in[15];

  float* out      = (float*)d_out;
  float* node_out = out;                          // [NN,64]
  float* edge_out = out + (size_t)NN * 64;        // [NE,32]

  float* ws = (float*)d_ws;
  unsigned* pqk = (unsigned*)ws;                   // NN*256 uints (bf16 q+k rows, 51.2MB)
  float* pv     = (float*)(pqk + (size_t)NN * 256);// NN*256 floats
  uint4* qwkw   = (uint4*)(pv + (size_t)NN * 256); // NE uint4
  float* wt_qn  = (float*)(qwkw + NE);             // 16384
  float* wt_kn  = wt_qn + 16384;
  float* wt_vn  = wt_kn + 16384;
  float* wt_ve  = wt_vn + 16384;                   // 4096
  float* wt_qe  = wt_ve + 4096;                    // 128
  float* wt_ke  = wt_qe + 128;                     // 128
  int* counts   = (int*)(wt_ke + 128);             // NN
  int* cursor   = counts + NN;                     // NN
  int* offsets  = cursor + NN;                     // NN+1 (+1 pad for alignment)
  int2* csr2    = (int2*)(offsets + NN + 2);       // NE pairs (8B aligned)
  int* bsums    = (int*)(csr2 + NE);               // 64

  // zero counts + cursor (contiguous)
  hipMemsetAsync(counts, 0, (size_t)2 * NN * sizeof(int), stream);

  // all weight transposes in one launch
  k_transpose_all<<<210, 256, 0, stream>>>(
      qn_w, kn_w, vn_w, ve_w, qe_w, ke_w,
      wt_qn, wt_kn, wt_vn, wt_ve, wt_qe, wt_ke);

  // edge gates (1 atomic/edge) then value GEMM (einp stays hot in L3)
  k_edge_gate<<<NE / 256, 256, 0, stream>>>(
      edge_inputs, dstv, wt_qe, qe_b, wt_ke, ke_b, counts, qwkw);
  k_edge_gemm<<<NE / 256, 256, 0, stream>>>(
      edge_inputs, qwkw, wt_ve, ve_b, edge_out);

  // node projections (q,k -> packed bf16; v -> fp32)
  k_node_proj<<<dim3((NN + 255) / 256, 3), 256, 0, stream>>>(
      node_inputs, wt_qn, qn_b, wt_kn, kn_b, wt_vn, vn_b, pqk, pv);

  // CSR build
  const int SB = (NN + 1023) / 1024;  // 49
  k_scan1<<<SB, 1024, 0, stream>>>(counts, offsets, bsums);
  k_scan2<<<1, 64, 0, stream>>>(bsums, SB);
  k_scan3<<<SB, 1024, 0, stream>>>(offsets, bsums);
  k_fill<<<NE / 256, 256, 0, stream>>>(dstv, srcv, offsets, cursor, csr2);

  // node aggregation + attention + output
  k_node_agg<<<NN / 4, 256, 0, stream>>>(
      offsets, csr2, qwkw, (const uint4*)pqk, pv, node_out);
}